// Round 6
// baseline (408.184 us; speedup 1.0000x reference)
//
#include <hip/hip_runtime.h>

#define N_NODES 100000
#define E_EDGES 1600000
// D = HID = 128, H = 4, HD = 32

typedef unsigned short u16;
typedef unsigned int   u32;
typedef unsigned char  u8;
typedef float f32x4  __attribute__((ext_vector_type(4)));
typedef short bf16x8 __attribute__((ext_vector_type(8)));

#define NBUK 98            // buckets of 1024 nodes: bucket = tgt >> 10
#define BCAP 20480         // fixed bucket capacity (mean 16384, +32 sigma)
#define MBLOCKS 1563       // ceil(N_NODES/64)
#define ECHUNKS 391        // ceil(E_EDGES/4096)
#define NDPAD 100352       // nodedeg array size (1024-aligned)

__device__ __forceinline__ u16 f2b(float f) {
  u32 b = __float_as_uint(f);
  return (u16)((b + 0x7FFFu + ((b >> 16) & 1u)) >> 16);
}
__device__ __forceinline__ float blo(u32 u) { return __uint_as_float(u << 16); }
__device__ __forceinline__ float bhi(u32 u) { return __uint_as_float(u & 0xFFFF0000u); }

// f32 -> OCP e4m3fn, round-to-nearest-even. |f| must be < 448 (holds: |K|<2).
__device__ __forceinline__ u8 f2e4m3(float f) {
  u32 b = __float_as_uint(f);
  u32 s = (b >> 24) & 0x80u;
  float y = __uint_as_float(b & 0x7fffffffu) * 0x1p-120f;
  u32 u = __float_as_uint(y);
  u += 0x7FFFFu + ((u >> 20) & 1u);
  return (u8)(s | ((u >> 20) & 0x7fu));
}

// fallback single-byte e4m3fn -> f32
__device__ __forceinline__ float e4m3_1(u32 x) {
  u32 y = ((x & 0x80u) << 24) | ((x & 0x7fu) << 20);
  return __uint_as_float(y) * 0x1p120f;
}

// decode 4 packed e4m3fn bytes -> 4 floats
__device__ __forceinline__ void dec4(u32 kq, float& k0, float& k1, float& k2, float& k3) {
#if __has_builtin(__builtin_amdgcn_cvt_pk_f32_fp8)
  auto lo = __builtin_amdgcn_cvt_pk_f32_fp8((int)kq, false);   // bytes 0,1
  auto hi = __builtin_amdgcn_cvt_pk_f32_fp8((int)kq, true);    // bytes 2,3
  k0 = lo[0]; k1 = lo[1]; k2 = hi[0]; k3 = hi[1];
#else
  k0 = e4m3_1(kq); k1 = e4m3_1(kq >> 8); k2 = e4m3_1(kq >> 16); k3 = e4m3_1(kq >> 24);
#endif
}

template<int CTRL>
__device__ __forceinline__ float dpp_add(float d) {
  int x = __builtin_amdgcn_update_dpp(0, __float_as_int(d), CTRL, 0xf, 0xf, true);
  return d + __int_as_float(x);
}
// Reduce across an 8-lane group: xor1, xor2 (quad_perm), then half-row mirror.
__device__ __forceinline__ float reduce8(float d) {
  d = dpp_add<0xB1>(d);    // quad_perm [1,0,3,2]
  d = dpp_add<0x4E>(d);    // quad_perm [2,3,0,1]
  d = dpp_add<0x141>(d);   // row_half_mirror
  return d;
}

// ---------------------------------------------------------------------------
// setup: init bucket cursors to fixed window bases AND transpose+convert W.
// ---------------------------------------------------------------------------
__global__ __launch_bounds__(256) void setup(
    const float* __restrict__ Wq, const float* __restrict__ Wk,
    const float* __restrict__ Wv, const float* __restrict__ Wo,
    u16* __restrict__ Wt, u32* __restrict__ bcur)
{
  int tid = blockIdx.x * 256 + threadIdx.x;
  if (tid < NBUK) bcur[tid] = (u32)tid * BCAP;
  int idx = tid - NBUK;
  if (idx >= 0 && idx < 65536) {
    int mat = idx >> 14;
    int rem = idx & 16383;
    int n = rem >> 7, k = rem & 127;
    const float* W = (mat == 0) ? Wq : (mat == 1) ? Wk : (mat == 2) ? Wv : Wo;
    Wt[idx] = f2b(W[k * 128 + n]);
  }
}

// ---------------------------------------------------------------------------
// Fused block-role kernel: blocks [0, MBLOCKS) run the QKV GEMM; blocks
// [MBLOCKS, MBLOCKS+ECHUNKS) run pass1 edge binning (now also producing the
// global per-node degree histogram via fire-and-forget atomics).
// Manual LDS aliasing: one 52224 B arena, laid out per role.
// ---------------------------------------------------------------------------
__global__ __launch_bounds__(256) void qkv_pass1(
    const float* __restrict__ A, const u16* __restrict__ Wt,
    const float* __restrict__ bq, const float* __restrict__ bk,
    const float* __restrict__ bv,
    u16* __restrict__ Qb, u8* __restrict__ Kf8, u16* __restrict__ Vb16, int M,
    const int* __restrict__ ei, const float* __restrict__ ew,
    u32* __restrict__ bcur, uint2* __restrict__ stag,
    u32* __restrict__ nodedeg)
{
  __shared__ __align__(16) char smem[52224];
  const int t = threadIdx.x;

  if ((int)blockIdx.x < MBLOCKS) {
    // ---------------- QKV GEMM role ----------------
    typedef u16 row136[136];
    row136* Alds = (row136*)smem;              // 64 x 136 u16 = 17408 B
    row136* Blds = (row136*)(smem + 17408);    // 128 x 136 u16 = 34816 B
    const int row0 = blockIdx.x * 64;

#pragma unroll
    for (int i = 0; i < 8; ++i) {
      int f = t + i * 256;
      int r = f >> 5, c4 = f & 31;
      int gr = row0 + r; if (gr >= M) gr = M - 1;
      float4 v = ((const float4*)(A + (size_t)gr * 128))[c4];
      u32* dst = (u32*)&Alds[r][c4 * 4];
      dst[0] = (u32)f2b(v.x) | ((u32)f2b(v.y) << 16);
      dst[1] = (u32)f2b(v.z) | ((u32)f2b(v.w) << 16);
    }

    const int lane = t & 63;
    const int mrow = lane & 15;
    const int q    = lane >> 4;
    const int m0   = (t >> 6) * 16;

    // W(0) prefetched to registers; next matrix prefetched during MFMA+epilogue
    uint4 wreg[8], wnxt[8];
#pragma unroll
    for (int i = 0; i < 8; ++i) {
      int f = t + i * 256;
      int r = f >> 4, c8 = f & 15;
      wreg[i] = ((const uint4*)(Wt + (size_t)r * 128))[c8];
    }

    for (int m = 0; m < 3; ++m) {
      __syncthreads();   // Blds free (prev epilogue done reading it)
#pragma unroll
      for (int i = 0; i < 8; ++i) {
        int f = t + i * 256;
        int r = f >> 4, c8 = f & 15;
        *(uint4*)&Blds[r][c8 * 8] = wreg[i];
      }
      if (m < 2) {
#pragma unroll
        for (int i = 0; i < 8; ++i) {
          int f = t + i * 256;
          int r = f >> 4, c8 = f & 15;
          wnxt[i] = ((const uint4*)(Wt + (size_t)(m + 1) * 16384 + (size_t)r * 128))[c8];
        }
      }
      __syncthreads();

      f32x4 acc[8];
#pragma unroll
      for (int c = 0; c < 8; ++c) acc[c] = (f32x4){0.f, 0.f, 0.f, 0.f};
#pragma unroll
      for (int kk = 0; kk < 4; ++kk) {
        const int kb = kk * 32 + q * 8;
        bf16x8 a = *(const bf16x8*)&Alds[m0 + mrow][kb];
#pragma unroll
        for (int c = 0; c < 8; ++c) {
          bf16x8 b = *(const bf16x8*)&Blds[c * 16 + mrow][kb];
          acc[c] = __builtin_amdgcn_mfma_f32_16x16x32_bf16(a, b, acc[c], 0, 0, 0);
        }
      }

      const float* bias = (m == 0) ? bq : (m == 1) ? bk : bv;
      __syncthreads();   // all waves done reading Blds -> reuse as staging
      if (m == 1) {
        // K: stage e4m3 bytes, then coalesced uint4 stores (8 KB tile)
        u8* Kst = (u8*)Blds;
#pragma unroll
        for (int c = 0; c < 8; ++c) {
          int gcol = c * 16 + mrow;
          float bvv = bias[gcol];
#pragma unroll
          for (int r = 0; r < 4; ++r)
            Kst[(m0 + q * 4 + r) * 128 + gcol] = f2e4m3(acc[c][r] + bvv);
        }
        __syncthreads();
#pragma unroll
        for (int i = 0; i < 2; ++i) {
          int f = t + i * 256;
          int r = f >> 3, c16 = f & 7;
          int grow = row0 + r;
          if (grow < M)
            *(uint4*)(Kf8 + (size_t)grow * 128 + c16 * 16) =
                *(const uint4*)(Kst + r * 128 + c16 * 16);
        }
      } else {
        // Q / V: stage bf16, then coalesced uint4 stores (16 KB tile)
        u16* St = (u16*)Blds;
#pragma unroll
        for (int c = 0; c < 8; ++c) {
          int gcol = c * 16 + mrow;
          float bvv = bias[gcol];
#pragma unroll
          for (int r = 0; r < 4; ++r)
            St[(m0 + q * 4 + r) * 128 + gcol] = f2b(acc[c][r] + bvv);
        }
        __syncthreads();
        u16* dstM = (m == 0) ? Qb : Vb16;
#pragma unroll
        for (int i = 0; i < 4; ++i) {
          int f = t + i * 256;
          int r = f >> 4, c8 = f & 15;
          int grow = row0 + r;
          if (grow < M)
            *(uint4*)(dstM + (size_t)grow * 128 + c8 * 8) =
                *(const uint4*)(St + r * 128 + c8 * 8);
        }
      }
#pragma unroll
      for (int i = 0; i < 8; ++i) wreg[i] = wnxt[i];
    }
  } else {
    // ---------------- pass1 edge-binning role ----------------
    u32* s_px    = (u32*)smem;               // 4096 u32
    u32* s_py    = (u32*)(smem + 16384);     // 4096 u32
    u32* s_gp    = (u32*)(smem + 32768);     // 4096 u32
    u32* s_hist  = (u32*)(smem + 49152);     // NBUK
    u32* s_excl  = (u32*)(smem + 49544);     // NBUK
    u32* s_gbase = (u32*)(smem + 49936);     // NBUK
    u32* s_wsum  = (u32*)(smem + 50328);     // 4

    const int base = ((int)blockIdx.x - MBLOCKS) * 4096;
    const int nv = min(4096, E_EDGES - base);   // nv % 4 == 0 always

    if (t < NBUK) s_hist[t] = 0;
    __syncthreads();

    u32 tg[16], py[16];
    const int4*   src4 = (const int4*)(ei + base);
    const int4*   tgt4 = (const int4*)(ei + E_EDGES + base);
    const float4* ewv4 = (const float4*)(ew + base);
#pragma unroll
    for (int j = 0; j < 4; ++j) {
      int q4 = t + j * 256;                 // int4 index
      bool valid = (q4 * 4) < nv;           // whole-vector validity (nv%4==0)
      int qq = valid ? q4 : 0;
      int4   sv = src4[qq];
      int4   tv = tgt4[qq];
      float4 wv = ewv4[qq];
      u32* TG = &tg[j * 4];
      u32* PY = &py[j * 4];
      TG[0] = (u32)tv.x; TG[1] = (u32)tv.y; TG[2] = (u32)tv.z; TG[3] = (u32)tv.w;
      PY[0] = ((u32)sv.x << 15) | (u32)(wv.x * 32768.0f);
      PY[1] = ((u32)sv.y << 15) | (u32)(wv.y * 32768.0f);
      PY[2] = ((u32)sv.z << 15) | (u32)(wv.z * 32768.0f);
      PY[3] = ((u32)sv.w << 15) | (u32)(wv.w * 32768.0f);
      if (valid) {
        atomicAdd(&s_hist[TG[0] >> 10], 1u);
        atomicAdd(&s_hist[TG[1] >> 10], 1u);
        atomicAdd(&s_hist[TG[2] >> 10], 1u);
        atomicAdd(&s_hist[TG[3] >> 10], 1u);
        // global per-node degree (fire-and-forget; consumed by pass2)
        atomicAdd(&nodedeg[TG[0]], 1u);
        atomicAdd(&nodedeg[TG[1]], 1u);
        atomicAdd(&nodedeg[TG[2]], 1u);
        atomicAdd(&nodedeg[TG[3]], 1u);
      } else {
        TG[0] = TG[1] = TG[2] = TG[3] = 0xFFFFFFFFu;
      }
    }
    __syncthreads();

    // scan 98 bucket counts: 64-lane shfl scans + cross-wave fixup
    {
      int v = (t < NBUK) ? (int)s_hist[t] : 0;
      int x = v;
#pragma unroll
      for (int d = 1; d < 64; d <<= 1) {
        int y = __shfl_up(x, d, 64);
        if ((t & 63) >= d) x += y;
      }
      if ((t & 63) == 63 && t < 128) s_wsum[t >> 6] = (u32)x;
      __syncthreads();
      if (t < NBUK) {
        int incl = x + ((t >= 64) ? (int)s_wsum[0] : 0);
        s_excl[t] = (u32)(incl - v);
        s_gbase[t] = (v > 0) ? atomicAdd(&bcur[t], (u32)v) : 0u;
      }
    }
    __syncthreads();
    if (t < NBUK) s_hist[t] = s_excl[t];   // reuse as LDS cursor
    __syncthreads();

#pragma unroll
    for (int i = 0; i < 16; ++i) {
      if (tg[i] != 0xFFFFFFFFu) {
        u32 bk = tg[i] >> 10;
        u32 lp = atomicAdd(&s_hist[bk], 1u);
        s_px[lp] = tg[i];
        s_py[lp] = py[i];
        s_gp[lp] = s_gbase[bk] + (lp - s_excl[bk]);
      }
    }
    __syncthreads();
    for (int s = t; s < nv; s += 256)
      stag[s_gp[s]] = make_uint2(s_px[s], s_py[s]);
  }
}

// ---------------------------------------------------------------------------
// Final: out(Mx128,f32) = A(bf16, Mx128) @ Wo + bo
// Epilogue staged through LDS -> coalesced NONTEMPORAL float4 stores
// (51.2 MB with no consumer -> don't pollute L2).
// ---------------------------------------------------------------------------
__global__ __launch_bounds__(256) void gemm_out(
    const u16* __restrict__ A, const u16* __restrict__ Wt,
    const float* __restrict__ bias, float* __restrict__ Cout, int M)
{
  __shared__ __align__(16) u16 Alds[64][136];
  __shared__ __align__(16) u16 Blds[128][136];
  const int t = threadIdx.x;
  const int row0 = blockIdx.x * 64;

#pragma unroll
  for (int i = 0; i < 4; ++i) {
    int f = t + i * 256;
    int r = f >> 4, c8 = f & 15;
    int gr = row0 + r; if (gr >= M) gr = M - 1;
    uint4 v = ((const uint4*)(A + (size_t)gr * 128))[c8];
    *(uint4*)&Alds[r][c8 * 8] = v;
  }
#pragma unroll
  for (int i = 0; i < 8; ++i) {
    int f = t + i * 256;
    int r = f >> 4, c8 = f & 15;
    uint4 v = ((const uint4*)(Wt + (size_t)r * 128))[c8];
    *(uint4*)&Blds[r][c8 * 8] = v;
  }
  __syncthreads();

  const int lane = t & 63;
  const int mrow = lane & 15;
  const int q    = lane >> 4;
  const int m0   = (t >> 6) * 16;

  f32x4 acc[8];
#pragma unroll
  for (int c = 0; c < 8; ++c) acc[c] = (f32x4){0.f, 0.f, 0.f, 0.f};
#pragma unroll
  for (int kk = 0; kk < 4; ++kk) {
    const int kb = kk * 32 + q * 8;
    bf16x8 a = *(const bf16x8*)&Alds[m0 + mrow][kb];
#pragma unroll
    for (int c = 0; c < 8; ++c) {
      bf16x8 b = *(const bf16x8*)&Blds[c * 16 + mrow][kb];
      acc[c] = __builtin_amdgcn_mfma_f32_16x16x32_bf16(a, b, acc[c], 0, 0, 0);
    }
  }

  // stage f32 tile (64 x 128, padded stride 132) into Blds memory
  __syncthreads();   // all waves done reading Blds
  float* Fst = (float*)&Blds[0][0];
#pragma unroll
  for (int c = 0; c < 8; ++c) {
    int gcol = c * 16 + mrow;
    float bv = bias[gcol];
#pragma unroll
    for (int r = 0; r < 4; ++r)
      Fst[(m0 + q * 4 + r) * 132 + gcol] = acc[c][r] + bv;
  }
  __syncthreads();
#pragma unroll
  for (int i = 0; i < 8; ++i) {
    int f = t + i * 256;
    int r = f >> 5, c4 = f & 31;
    int grow = row0 + r;
    if (grow < M) {
      f32x4 vv = *(const f32x4*)(Fst + r * 132 + c4 * 4);
      __builtin_nontemporal_store(vv, (f32x4*)(Cout + (size_t)grow * 128 + c4 * 4));
    }
  }
}

// ---------------------------------------------------------------------------
// pass2: one block per bucket. Degrees come precomputed from pass1's global
// histogram (coalesced load, no stag re-read); shfl scan -> nodeinfo
// {start,deg}; then ONE streaming pass over stag (nontemporal loads —
// single-use stream, keep K/V warm for gather) scattering into the bucket's
// csr window via LDS cursors.
// ---------------------------------------------------------------------------
__global__ __launch_bounds__(1024) void pass2_scatter(
    const u32* __restrict__ bcur, const u32* __restrict__ nodedeg,
    const uint2* __restrict__ stag,
    int2* __restrict__ nodeinfo, u32* __restrict__ csr)
{
  __shared__ int s_cur[1024];
  __shared__ int s_wsum[16];
  const int t = threadIdx.x;
  const int b = blockIdx.x;
  const int sb = b * BCAP;
  const int cnt = (int)bcur[b] - sb;
  const int node_base = b << 10;
  const int node = node_base + t;

  // degree (nodedeg is NDPAD-sized and zeroed, so node index is always safe)
  int v = (int)nodedeg[node];

  // hierarchical inclusive scan of 1024 degrees
  int x = v;
#pragma unroll
  for (int d = 1; d < 64; d <<= 1) {
    int y = __shfl_up(x, d, 64);
    if ((t & 63) >= d) x += y;
  }
  if ((t & 63) == 63) s_wsum[t >> 6] = x;
  __syncthreads();
  if (t < 64) {
    int w = (t < 16) ? s_wsum[t] : 0;
#pragma unroll
    for (int d = 1; d < 16; d <<= 1) {
      int y = __shfl_up(w, d, 64);
      if (t >= d) w += y;
    }
    if (t < 16) s_wsum[t] = w;   // inclusive wave-sum prefix
  }
  __syncthreads();
  int wbase = (t >= 64) ? s_wsum[(t >> 6) - 1] : 0;
  int excl = x + wbase - v;
  if (node < N_NODES) nodeinfo[node] = make_int2(sb + excl, v);
  s_cur[t] = sb + excl;   // absolute cursor
  __syncthreads();

  // single streaming scatter pass, 4-batched, NT loads
  typedef unsigned long long u64;
  const u64* sg = (const u64*)stag;
  int i = t;
  for (; i + 3072 < cnt; i += 4096) {
    u64 e0 = __builtin_nontemporal_load(sg + sb + i);
    u64 e1 = __builtin_nontemporal_load(sg + sb + i + 1024);
    u64 e2 = __builtin_nontemporal_load(sg + sb + i + 2048);
    u64 e3 = __builtin_nontemporal_load(sg + sb + i + 3072);
    int p0 = atomicAdd(&s_cur[(u32)e0 & 1023u], 1);
    int p1 = atomicAdd(&s_cur[(u32)e1 & 1023u], 1);
    int p2 = atomicAdd(&s_cur[(u32)e2 & 1023u], 1);
    int p3 = atomicAdd(&s_cur[(u32)e3 & 1023u], 1);
    csr[p0] = (u32)(e0 >> 32);
    csr[p1] = (u32)(e1 >> 32);
    csr[p2] = (u32)(e2 >> 32);
    csr[p3] = (u32)(e3 >> 32);
  }
  for (; i < cnt; i += 1024) {
    u64 e = __builtin_nontemporal_load(sg + sb + i);
    int pos = atomicAdd(&s_cur[(u32)e & 1023u], 1);
    csr[pos] = (u32)(e >> 32);
  }
}

// ---------------------------------------------------------------------------
// Fused per-node gather, 2 edges per wave (lanes 0-31 even edges, 32-63 odd),
// 4-pair unroll -> 8 edges in flight per wave.  [FROZEN since round 3]
// Within a half: 8 lanes/head, lane owns elems [4hl..4hl+3]:
//   K: one dword of fp8 at Krow + 4*hl   (row = 128 B = 1 cache line)
//   V: one dwordx2 of bf16 at Vrow + 8*hl (row = 256 B = 2 lines)
// ---------------------------------------------------------------------------
__global__ __launch_bounds__(256) void gather_fused(
    const int2* __restrict__ nodeinfo, const u32* __restrict__ csr,
    u32* __restrict__ Qb32, const u8* __restrict__ Kf8,
    const u32* __restrict__ Vb,
    const float* __restrict__ We, const float* __restrict__ be)
{
  int node = blockIdx.x * 4 + (threadIdx.x >> 6);
  int l    = threadIdx.x & 63;
  int half = l >> 5;
  int hl   = l & 31;
  int h    = hl >> 3;

  const float scale = 0.17677669529663687f;   // 1/sqrt(32)
  const float eiq   = 1.0f / 32768.0f;
  uint2 qp = *(const uint2*)(Qb32 + (size_t)node * 64 + hl * 2);
  float qa = blo(qp.x) * scale, qb = bhi(qp.x) * scale;
  float qc = blo(qp.y) * scale, qd = bhi(qp.y) * scale;
  float weq = We[h] * eiq, bE = be[h];
  const u32 laneK = (u32)hl * 4;
  const u32 laneV = (u32)hl * 8;

  int2 ni = nodeinfo[node];
  int s0 = ni.x, L = ni.y;
  int npair = L >> 1;
  const u32* cp = csr + s0 + half;
  const char* Kc = (const char*)Kf8;
  const char* Vc = (const char*)Vb;

  float a0 = 0.f, a1 = 0.f, a2 = 0.f, a3 = 0.f, sum = 0.f;

  auto LDK = [&](u32 c) -> u32 {
    return *(const u32*)(Kc + (((c >> 15) << 7) + laneK));
  };
  auto LDV = [&](u32 c) -> uint2 {
    return *(const uint2*)(Vc + (((c >> 15) << 8) + laneV));
  };
  auto COMP = [&](u32 c, u32 kq, uint2 vv) {
    float k0, k1, k2, k3;
    dec4(kq, k0, k1, k2, k3);
    float d = qa * k0 + qb * k1 + qc * k2 + qd * k3;
    d = reduce8(d);
    float p = __expf(d + (float)(c & 32767u) * weq + bE);
    sum += p;
    a0 += p * blo(vv.x);
    a1 += p * bhi(vv.x);
    a2 += p * blo(vv.y);
    a3 += p * bhi(vv.y);
  };

  int i = 0;
  for (; i + 4 <= npair; i += 4) {
    u32 c0 = cp[2 * i];
    u32 c1 = cp[2 * i + 2];
    u32 c2 = cp[2 * i + 4];
    u32 c3 = cp[2 * i + 6];
    u32 k0 = LDK(c0), k1 = LDK(c1), k2 = LDK(c2), k3 = LDK(c3);
    uint2 v0 = LDV(c0), v1 = LDV(c1), v2 = LDV(c2), v3 = LDV(c3);
    COMP(c0, k0, v0);
    COMP(c1, k1, v1);
    COMP(c2, k2, v2);
    COMP(c3, k3, v3);
  }
  for (; i < npair; ++i) {
    u32 c = cp[2 * i];
    u32 kq = LDK(c);
    uint2 vv = LDV(c);
    COMP(c, kq, vv);
  }
  // odd final edge: both halves load it, half 1 contributes 0
  if (L & 1) {
    u32 c = csr[s0 + L - 1];
    u32 kq = LDK(c);
    uint2 vv = LDV(c);
    float k0, k1, k2, k3;
    dec4(kq, k0, k1, k2, k3);
    float d = qa * k0 + qb * k1 + qc * k2 + qd * k3;
    d = reduce8(d);
    float p = __expf(d + (float)(c & 32767u) * weq + bE);
    p = half ? 0.f : p;
    sum += p;
    a0 += p * blo(vv.x);
    a1 += p * bhi(vv.x);
    a2 += p * blo(vv.y);
    a3 += p * bhi(vv.y);
  }

  sum += __shfl_xor(sum, 32, 64);
  a0  += __shfl_xor(a0, 32, 64);
  a1  += __shfl_xor(a1, 32, 64);
  a2  += __shfl_xor(a2, 32, 64);
  a3  += __shfl_xor(a3, 32, 64);

  float inv = 1.f / (sum + 1e-8f);
  if (half == 0) {
    uint2 w;
    w.x = (u32)f2b(a0 * inv) | ((u32)f2b(a1 * inv) << 16);
    w.y = (u32)f2b(a2 * inv) | ((u32)f2b(a3 * inv) << 16);
    *(uint2*)(Qb32 + (size_t)node * 64 + hl * 2) = w;
  }
}

// ---------------------------------------------------------------------------
extern "C" void kernel_launch(void* const* d_in, const int* in_sizes, int n_in,
                              void* d_out, int out_size, void* d_ws, size_t ws_size,
                              hipStream_t stream) {
  const float* nf = (const float*)d_in[0];
  const int*   ei = (const int*)  d_in[1];
  const float* ew = (const float*)d_in[2];
  const float* Wq = (const float*)d_in[3];
  const float* bq = (const float*)d_in[4];
  const float* Wk = (const float*)d_in[5];
  const float* bk = (const float*)d_in[6];
  const float* Wv = (const float*)d_in[7];
  const float* bv = (const float*)d_in[8];
  const float* Wo = (const float*)d_in[9];
  const float* bo = (const float*)d_in[10];
  const float* We = (const float*)d_in[11];
  const float* be = (const float*)d_in[12];
  float* out = (float*)d_out;

  char* ws = (char*)d_ws;
  u16*  Wt  = (u16*)ws;                                 // 128 KB
  u16*  Qb  = (u16*)(ws + 131072);                      // 25.6 MB
  u8*   Kf8 = (u8*)(Qb + (size_t)N_NODES * 128);        // 12.8 MB
  u16*  Vb16 = (u16*)(Kf8 + (size_t)N_NODES * 128);     // 25.6 MB
  char* p   = (char*)(Vb16 + (size_t)N_NODES * 128);
  uint2* stag = (uint2*)p;              p += (size_t)NBUK * BCAP * 8;  // 16.1 MB
  u32*  csr = (u32*)p;                  p += (size_t)NBUK * BCAP * 4;  // 8.0 MB
  int2* nodeinfo = (int2*)p;            p += (size_t)N_NODES * 8;      // 0.8 MB
  u32*  bcur = (u32*)p;                 p += 512;
  u32*  nodedeg = (u32*)p;              p += (size_t)NDPAD * 4;        // 0.4 MB

  hipMemsetAsync(nodedeg, 0, (size_t)NDPAD * 4, stream);

  setup<<<(NBUK + 65536 + 255) / 256, 256, 0, stream>>>(Wq, Wk, Wv, Wo, Wt, bcur);

  qkv_pass1<<<MBLOCKS + ECHUNKS, 256, 0, stream>>>(
      nf, Wt, bq, bk, bv, Qb, Kf8, Vb16, N_NODES, ei, ew, bcur, stag, nodedeg);

  pass2_scatter<<<NBUK, 1024, 0, stream>>>(bcur, nodedeg, stag, nodeinfo, csr);

  gather_fused<<<N_NODES / 4, 256, 0, stream>>>(nodeinfo, csr,
      (u32*)Qb, Kf8, (const u32*)Vb16, We, be);

  gemm_out<<<MBLOCKS, 256, 0, stream>>>(Qb, Wt + 49152, bo, out, N_NODES);
}

// Round 7
// 278.299 us; speedup vs baseline: 1.4667x; 1.4667x over previous
//
#include <hip/hip_runtime.h>

#define N_NODES 100000
#define E_EDGES 1600000
// D = HID = 128, H = 4, HD = 32

typedef unsigned short u16;
typedef unsigned int   u32;
typedef unsigned char  u8;
typedef float f32x4  __attribute__((ext_vector_type(4)));
typedef short bf16x8 __attribute__((ext_vector_type(8)));

#define NBUK 98            // buckets of 1024 nodes: bucket = tgt >> 10
#define BCAP 20480         // fixed bucket capacity (mean 16384, +32 sigma)
#define MBLOCKS 1563       // ceil(N_NODES/64)
#define ECHUNKS 391        // ceil(E_EDGES/4096)

__device__ __forceinline__ u16 f2b(float f) {
  u32 b = __float_as_uint(f);
  return (u16)((b + 0x7FFFu + ((b >> 16) & 1u)) >> 16);
}
__device__ __forceinline__ float blo(u32 u) { return __uint_as_float(u << 16); }
__device__ __forceinline__ float bhi(u32 u) { return __uint_as_float(u & 0xFFFF0000u); }

// f32 -> OCP e4m3fn, round-to-nearest-even. |f| must be < 448 (holds: |K|<2).
__device__ __forceinline__ u8 f2e4m3(float f) {
  u32 b = __float_as_uint(f);
  u32 s = (b >> 24) & 0x80u;
  float y = __uint_as_float(b & 0x7fffffffu) * 0x1p-120f;
  u32 u = __float_as_uint(y);
  u += 0x7FFFFu + ((u >> 20) & 1u);
  return (u8)(s | ((u >> 20) & 0x7fu));
}

// fallback single-byte e4m3fn -> f32
__device__ __forceinline__ float e4m3_1(u32 x) {
  u32 y = ((x & 0x80u) << 24) | ((x & 0x7fu) << 20);
  return __uint_as_float(y) * 0x1p120f;
}

// decode 4 packed e4m3fn bytes -> 4 floats
__device__ __forceinline__ void dec4(u32 kq, float& k0, float& k1, float& k2, float& k3) {
#if __has_builtin(__builtin_amdgcn_cvt_pk_f32_fp8)
  auto lo = __builtin_amdgcn_cvt_pk_f32_fp8((int)kq, false);   // bytes 0,1
  auto hi = __builtin_amdgcn_cvt_pk_f32_fp8((int)kq, true);    // bytes 2,3
  k0 = lo[0]; k1 = lo[1]; k2 = hi[0]; k3 = hi[1];
#else
  k0 = e4m3_1(kq); k1 = e4m3_1(kq >> 8); k2 = e4m3_1(kq >> 16); k3 = e4m3_1(kq >> 24);
#endif
}

template<int CTRL>
__device__ __forceinline__ float dpp_add(float d) {
  int x = __builtin_amdgcn_update_dpp(0, __float_as_int(d), CTRL, 0xf, 0xf, true);
  return d + __int_as_float(x);
}
// Reduce across an 8-lane group: xor1, xor2 (quad_perm), then half-row mirror.
__device__ __forceinline__ float reduce8(float d) {
  d = dpp_add<0xB1>(d);    // quad_perm [1,0,3,2]
  d = dpp_add<0x4E>(d);    // quad_perm [2,3,0,1]
  d = dpp_add<0x141>(d);   // row_half_mirror
  return d;
}

// ---------------------------------------------------------------------------
// setup: init bucket cursors to fixed window bases AND transpose+convert W.
// ---------------------------------------------------------------------------
__global__ __launch_bounds__(256) void setup(
    const float* __restrict__ Wq, const float* __restrict__ Wk,
    const float* __restrict__ Wv, const float* __restrict__ Wo,
    u16* __restrict__ Wt, u32* __restrict__ bcur)
{
  int tid = blockIdx.x * 256 + threadIdx.x;
  if (tid < NBUK) bcur[tid] = (u32)tid * BCAP;
  int idx = tid - NBUK;
  if (idx >= 0 && idx < 65536) {
    int mat = idx >> 14;
    int rem = idx & 16383;
    int n = rem >> 7, k = rem & 127;
    const float* W = (mat == 0) ? Wq : (mat == 1) ? Wk : (mat == 2) ? Wv : Wo;
    Wt[idx] = f2b(W[k * 128 + n]);
  }
}

// ---------------------------------------------------------------------------
// Fused block-role kernel: blocks [0, MBLOCKS) run the QKV GEMM; blocks
// [MBLOCKS, MBLOCKS+ECHUNKS) run pass1 edge binning.
// NO global atomics (round-6 lesson: scattered device-scope atomicAdd costs
// a full HBM line each — 6.4M of them = +410 MB write traffic).
// Epilogue staging strides padded (136 u16 / 144 B) to break the 4-way
// LDS store bank conflicts measured in round 6 (SQ_LDS_BANK_CONFLICT 4.7M).
// ---------------------------------------------------------------------------
__global__ __launch_bounds__(256) void qkv_pass1(
    const float* __restrict__ A, const u16* __restrict__ Wt,
    const float* __restrict__ bq, const float* __restrict__ bk,
    const float* __restrict__ bv,
    u16* __restrict__ Qb, u8* __restrict__ Kf8, u16* __restrict__ Vb16, int M,
    const int* __restrict__ ei, const float* __restrict__ ew,
    u32* __restrict__ bcur, uint2* __restrict__ stag)
{
  __shared__ __align__(16) char smem[52224];
  const int t = threadIdx.x;

  if ((int)blockIdx.x < MBLOCKS) {
    // ---------------- QKV GEMM role ----------------
    typedef u16 row136[136];
    row136* Alds = (row136*)smem;              // 64 x 136 u16 = 17408 B
    row136* Blds = (row136*)(smem + 17408);    // 128 x 136 u16 = 34816 B
    const int row0 = blockIdx.x * 64;

#pragma unroll
    for (int i = 0; i < 8; ++i) {
      int f = t + i * 256;
      int r = f >> 5, c4 = f & 31;
      int gr = row0 + r; if (gr >= M) gr = M - 1;
      float4 v = ((const float4*)(A + (size_t)gr * 128))[c4];
      u32* dst = (u32*)&Alds[r][c4 * 4];
      dst[0] = (u32)f2b(v.x) | ((u32)f2b(v.y) << 16);
      dst[1] = (u32)f2b(v.z) | ((u32)f2b(v.w) << 16);
    }

    const int lane = t & 63;
    const int mrow = lane & 15;
    const int q    = lane >> 4;
    const int m0   = (t >> 6) * 16;

    for (int m = 0; m < 3; ++m) {
      __syncthreads();
#pragma unroll
      for (int i = 0; i < 8; ++i) {
        int f = t + i * 256;
        int r = f >> 4, c8 = f & 15;
        uint4 v = ((const uint4*)(Wt + (size_t)m * 16384 + (size_t)r * 128))[c8];
        *(uint4*)&Blds[r][c8 * 8] = v;
      }
      __syncthreads();

      f32x4 acc[8];
#pragma unroll
      for (int c = 0; c < 8; ++c) acc[c] = (f32x4){0.f, 0.f, 0.f, 0.f};
#pragma unroll
      for (int kk = 0; kk < 4; ++kk) {
        const int kb = kk * 32 + q * 8;
        bf16x8 a = *(const bf16x8*)&Alds[m0 + mrow][kb];
#pragma unroll
        for (int c = 0; c < 8; ++c) {
          bf16x8 b = *(const bf16x8*)&Blds[c * 16 + mrow][kb];
          acc[c] = __builtin_amdgcn_mfma_f32_16x16x32_bf16(a, b, acc[c], 0, 0, 0);
        }
      }

      const float* bias = (m == 0) ? bq : (m == 1) ? bk : bv;
      __syncthreads();   // all waves done reading Blds -> reuse as staging
      if (m == 1) {
        // K: stage e4m3 bytes (row stride 144 B, 16B-aligned, conflict-padded)
        u8* Kst = (u8*)Blds;
#pragma unroll
        for (int c = 0; c < 8; ++c) {
          int gcol = c * 16 + mrow;
          float bvv = bias[gcol];
#pragma unroll
          for (int r = 0; r < 4; ++r)
            Kst[(m0 + q * 4 + r) * 144 + gcol] = f2e4m3(acc[c][r] + bvv);
        }
        __syncthreads();
#pragma unroll
        for (int i = 0; i < 2; ++i) {
          int f = t + i * 256;
          int r = f >> 3, c16 = f & 7;
          int grow = row0 + r;
          if (grow < M)
            *(uint4*)(Kf8 + (size_t)grow * 128 + c16 * 16) =
                *(const uint4*)(Kst + r * 144 + c16 * 16);
        }
      } else {
        // Q / V: stage bf16 (row stride 136 u16 = 272 B, 16B-aligned, padded)
        u16* St = (u16*)Blds;
#pragma unroll
        for (int c = 0; c < 8; ++c) {
          int gcol = c * 16 + mrow;
          float bvv = bias[gcol];
#pragma unroll
          for (int r = 0; r < 4; ++r)
            St[(m0 + q * 4 + r) * 136 + gcol] = f2b(acc[c][r] + bvv);
        }
        __syncthreads();
        u16* dstM = (m == 0) ? Qb : Vb16;
#pragma unroll
        for (int i = 0; i < 4; ++i) {
          int f = t + i * 256;
          int r = f >> 4, c8 = f & 15;
          int grow = row0 + r;
          if (grow < M)
            *(uint4*)(dstM + (size_t)grow * 128 + c8 * 8) =
                *(const uint4*)(St + r * 136 + c8 * 8);
        }
      }
    }
  } else {
    // ---------------- pass1 edge-binning role ----------------
    u32* s_px    = (u32*)smem;               // 4096 u32
    u32* s_py    = (u32*)(smem + 16384);     // 4096 u32
    u32* s_gp    = (u32*)(smem + 32768);     // 4096 u32
    u32* s_hist  = (u32*)(smem + 49152);     // NBUK
    u32* s_excl  = (u32*)(smem + 49544);     // NBUK
    u32* s_gbase = (u32*)(smem + 49936);     // NBUK
    u32* s_wsum  = (u32*)(smem + 50328);     // 4

    const int base = ((int)blockIdx.x - MBLOCKS) * 4096;
    const int nv = min(4096, E_EDGES - base);   // nv % 4 == 0 always

    if (t < NBUK) s_hist[t] = 0;
    __syncthreads();

    u32 tg[16], py[16];
    const int4*   src4 = (const int4*)(ei + base);
    const int4*   tgt4 = (const int4*)(ei + E_EDGES + base);
    const float4* ewv4 = (const float4*)(ew + base);
#pragma unroll
    for (int j = 0; j < 4; ++j) {
      int q4 = t + j * 256;                 // int4 index
      bool valid = (q4 * 4) < nv;           // whole-vector validity (nv%4==0)
      int qq = valid ? q4 : 0;
      int4   sv = src4[qq];
      int4   tv = tgt4[qq];
      float4 wv = ewv4[qq];
      u32* TG = &tg[j * 4];
      u32* PY = &py[j * 4];
      TG[0] = (u32)tv.x; TG[1] = (u32)tv.y; TG[2] = (u32)tv.z; TG[3] = (u32)tv.w;
      PY[0] = ((u32)sv.x << 15) | (u32)(wv.x * 32768.0f);
      PY[1] = ((u32)sv.y << 15) | (u32)(wv.y * 32768.0f);
      PY[2] = ((u32)sv.z << 15) | (u32)(wv.z * 32768.0f);
      PY[3] = ((u32)sv.w << 15) | (u32)(wv.w * 32768.0f);
      if (valid) {
        atomicAdd(&s_hist[TG[0] >> 10], 1u);
        atomicAdd(&s_hist[TG[1] >> 10], 1u);
        atomicAdd(&s_hist[TG[2] >> 10], 1u);
        atomicAdd(&s_hist[TG[3] >> 10], 1u);
      } else {
        TG[0] = TG[1] = TG[2] = TG[3] = 0xFFFFFFFFu;
      }
    }
    __syncthreads();

    // scan 98 bucket counts: 64-lane shfl scans + cross-wave fixup
    {
      int v = (t < NBUK) ? (int)s_hist[t] : 0;
      int x = v;
#pragma unroll
      for (int d = 1; d < 64; d <<= 1) {
        int y = __shfl_up(x, d, 64);
        if ((t & 63) >= d) x += y;
      }
      if ((t & 63) == 63 && t < 128) s_wsum[t >> 6] = (u32)x;
      __syncthreads();
      if (t < NBUK) {
        int incl = x + ((t >= 64) ? (int)s_wsum[0] : 0);
        s_excl[t] = (u32)(incl - v);
        s_gbase[t] = (v > 0) ? atomicAdd(&bcur[t], (u32)v) : 0u;
      }
    }
    __syncthreads();
    if (t < NBUK) s_hist[t] = s_excl[t];   // reuse as LDS cursor
    __syncthreads();

#pragma unroll
    for (int i = 0; i < 16; ++i) {
      if (tg[i] != 0xFFFFFFFFu) {
        u32 bk = tg[i] >> 10;
        u32 lp = atomicAdd(&s_hist[bk], 1u);
        s_px[lp] = tg[i];
        s_py[lp] = py[i];
        s_gp[lp] = s_gbase[bk] + (lp - s_excl[bk]);
      }
    }
    __syncthreads();
    for (int s = t; s < nv; s += 256)
      stag[s_gp[s]] = make_uint2(s_px[s], s_py[s]);
  }
}

// ---------------------------------------------------------------------------
// Final: out(Mx128,f32) = A(bf16, Mx128) @ Wo + bo
// Epilogue staged through LDS -> coalesced NONTEMPORAL float4 stores.
// ---------------------------------------------------------------------------
__global__ __launch_bounds__(256) void gemm_out(
    const u16* __restrict__ A, const u16* __restrict__ Wt,
    const float* __restrict__ bias, float* __restrict__ Cout, int M)
{
  __shared__ __align__(16) u16 Alds[64][136];
  __shared__ __align__(16) u16 Blds[128][136];
  const int t = threadIdx.x;
  const int row0 = blockIdx.x * 64;

#pragma unroll
  for (int i = 0; i < 4; ++i) {
    int f = t + i * 256;
    int r = f >> 4, c8 = f & 15;
    int gr = row0 + r; if (gr >= M) gr = M - 1;
    uint4 v = ((const uint4*)(A + (size_t)gr * 128))[c8];
    *(uint4*)&Alds[r][c8 * 8] = v;
  }
#pragma unroll
  for (int i = 0; i < 8; ++i) {
    int f = t + i * 256;
    int r = f >> 4, c8 = f & 15;
    uint4 v = ((const uint4*)(Wt + (size_t)r * 128))[c8];
    *(uint4*)&Blds[r][c8 * 8] = v;
  }
  __syncthreads();

  const int lane = t & 63;
  const int mrow = lane & 15;
  const int q    = lane >> 4;
  const int m0   = (t >> 6) * 16;

  f32x4 acc[8];
#pragma unroll
  for (int c = 0; c < 8; ++c) acc[c] = (f32x4){0.f, 0.f, 0.f, 0.f};
#pragma unroll
  for (int kk = 0; kk < 4; ++kk) {
    const int kb = kk * 32 + q * 8;
    bf16x8 a = *(const bf16x8*)&Alds[m0 + mrow][kb];
#pragma unroll
    for (int c = 0; c < 8; ++c) {
      bf16x8 b = *(const bf16x8*)&Blds[c * 16 + mrow][kb];
      acc[c] = __builtin_amdgcn_mfma_f32_16x16x32_bf16(a, b, acc[c], 0, 0, 0);
    }
  }

  // stage f32 tile (64 x 128, padded stride 132) into Blds memory
  __syncthreads();   // all waves done reading Blds
  float* Fst = (float*)&Blds[0][0];
#pragma unroll
  for (int c = 0; c < 8; ++c) {
    int gcol = c * 16 + mrow;
    float bv = bias[gcol];
#pragma unroll
    for (int r = 0; r < 4; ++r)
      Fst[(m0 + q * 4 + r) * 132 + gcol] = acc[c][r] + bv;
  }
  __syncthreads();
#pragma unroll
  for (int i = 0; i < 8; ++i) {
    int f = t + i * 256;
    int r = f >> 5, c4 = f & 31;
    int grow = row0 + r;
    if (grow < M) {
      f32x4 vv = *(const f32x4*)(Fst + r * 132 + c4 * 4);
      __builtin_nontemporal_store(vv, (f32x4*)(Cout + (size_t)grow * 128 + c4 * 4));
    }
  }
}

// ---------------------------------------------------------------------------
// pass2: one block per bucket. Single global read of stag into REGISTERS
// (20-deep unrolled, static-indexed, nontemporal); LDS per-node histogram +
// shfl scan -> nodeinfo {start,deg}; scatter from registers via LDS cursors
// into the bucket's csr window.  [round-5 structure — measured good]
// ---------------------------------------------------------------------------
__global__ __launch_bounds__(1024) void pass2_scatter(
    const u32* __restrict__ bcur, const uint2* __restrict__ stag,
    int2* __restrict__ nodeinfo, u32* __restrict__ csr)
{
  __shared__ int s_hist[1024];
  __shared__ int s_wsum[16];
  const int t = threadIdx.x;
  const int b = blockIdx.x;
  const int sb = b * BCAP;
  const int cnt = (int)bcur[b] - sb;
  const int node_base = b << 10;

  s_hist[t] = 0;
  __syncthreads();

  // single pass over stag: payload + node-id into registers, histogram to LDS
  typedef unsigned long long u64;
  const u64* sg = (const u64*)stag;
  u32 tgr[20], pyr[20];
#pragma unroll
  for (int k = 0; k < 20; ++k) {
    int i = t + k * 1024;
    if (i < cnt) {
      u64 e = __builtin_nontemporal_load(sg + sb + i);
      tgr[k] = (u32)e & 1023u;
      pyr[k] = (u32)(e >> 32);
      atomicAdd(&s_hist[tgr[k]], 1);
    } else {
      tgr[k] = 0xFFFFFFFFu;
      pyr[k] = 0u;
    }
  }
  __syncthreads();

  // hierarchical inclusive scan of 1024 counts
  int v = s_hist[t];
  int x = v;
#pragma unroll
  for (int d = 1; d < 64; d <<= 1) {
    int y = __shfl_up(x, d, 64);
    if ((t & 63) >= d) x += y;
  }
  if ((t & 63) == 63) s_wsum[t >> 6] = x;
  __syncthreads();
  if (t < 64) {
    int w = (t < 16) ? s_wsum[t] : 0;
#pragma unroll
    for (int d = 1; d < 16; d <<= 1) {
      int y = __shfl_up(w, d, 64);
      if (t >= d) w += y;
    }
    if (t < 16) s_wsum[t] = w;   // inclusive wave-sum prefix
  }
  __syncthreads();
  int wbase = (t >= 64) ? s_wsum[(t >> 6) - 1] : 0;
  int excl = x + wbase - v;
  int node = node_base + t;
  if (node < N_NODES) nodeinfo[node] = make_int2(sb + excl, v);
  __syncthreads();
  s_hist[t] = sb + excl;   // absolute cursor
  __syncthreads();

  // scatter from registers
#pragma unroll
  for (int k = 0; k < 20; ++k) {
    if (tgr[k] != 0xFFFFFFFFu) {
      int pos = atomicAdd(&s_hist[tgr[k]], 1);
      csr[pos] = pyr[k];
    }
  }
}

// ---------------------------------------------------------------------------
// Fused per-node gather, 2 edges per wave (lanes 0-31 even edges, 32-63 odd),
// 4-pair unroll -> 8 edges in flight per wave.  [FROZEN since round 3]
// Within a half: 8 lanes/head, lane owns elems [4hl..4hl+3]:
//   K: one dword of fp8 at Krow + 4*hl   (row = 128 B = 1 cache line)
//   V: one dwordx2 of bf16 at Vrow + 8*hl (row = 256 B = 2 lines)
// ---------------------------------------------------------------------------
__global__ __launch_bounds__(256) void gather_fused(
    const int2* __restrict__ nodeinfo, const u32* __restrict__ csr,
    u32* __restrict__ Qb32, const u8* __restrict__ Kf8,
    const u32* __restrict__ Vb,
    const float* __restrict__ We, const float* __restrict__ be)
{
  int node = blockIdx.x * 4 + (threadIdx.x >> 6);
  int l    = threadIdx.x & 63;
  int half = l >> 5;
  int hl   = l & 31;
  int h    = hl >> 3;

  const float scale = 0.17677669529663687f;   // 1/sqrt(32)
  const float eiq   = 1.0f / 32768.0f;
  uint2 qp = *(const uint2*)(Qb32 + (size_t)node * 64 + hl * 2);
  float qa = blo(qp.x) * scale, qb = bhi(qp.x) * scale;
  float qc = blo(qp.y) * scale, qd = bhi(qp.y) * scale;
  float weq = We[h] * eiq, bE = be[h];
  const u32 laneK = (u32)hl * 4;
  const u32 laneV = (u32)hl * 8;

  int2 ni = nodeinfo[node];
  int s0 = ni.x, L = ni.y;
  int npair = L >> 1;
  const u32* cp = csr + s0 + half;
  const char* Kc = (const char*)Kf8;
  const char* Vc = (const char*)Vb;

  float a0 = 0.f, a1 = 0.f, a2 = 0.f, a3 = 0.f, sum = 0.f;

  auto LDK = [&](u32 c) -> u32 {
    return *(const u32*)(Kc + (((c >> 15) << 7) + laneK));
  };
  auto LDV = [&](u32 c) -> uint2 {
    return *(const uint2*)(Vc + (((c >> 15) << 8) + laneV));
  };
  auto COMP = [&](u32 c, u32 kq, uint2 vv) {
    float k0, k1, k2, k3;
    dec4(kq, k0, k1, k2, k3);
    float d = qa * k0 + qb * k1 + qc * k2 + qd * k3;
    d = reduce8(d);
    float p = __expf(d + (float)(c & 32767u) * weq + bE);
    sum += p;
    a0 += p * blo(vv.x);
    a1 += p * bhi(vv.x);
    a2 += p * blo(vv.y);
    a3 += p * bhi(vv.y);
  };

  int i = 0;
  for (; i + 4 <= npair; i += 4) {
    u32 c0 = cp[2 * i];
    u32 c1 = cp[2 * i + 2];
    u32 c2 = cp[2 * i + 4];
    u32 c3 = cp[2 * i + 6];
    u32 k0 = LDK(c0), k1 = LDK(c1), k2 = LDK(c2), k3 = LDK(c3);
    uint2 v0 = LDV(c0), v1 = LDV(c1), v2 = LDV(c2), v3 = LDV(c3);
    COMP(c0, k0, v0);
    COMP(c1, k1, v1);
    COMP(c2, k2, v2);
    COMP(c3, k3, v3);
  }
  for (; i < npair; ++i) {
    u32 c = cp[2 * i];
    u32 kq = LDK(c);
    uint2 vv = LDV(c);
    COMP(c, kq, vv);
  }
  // odd final edge: both halves load it, half 1 contributes 0
  if (L & 1) {
    u32 c = csr[s0 + L - 1];
    u32 kq = LDK(c);
    uint2 vv = LDV(c);
    float k0, k1, k2, k3;
    dec4(kq, k0, k1, k2, k3);
    float d = qa * k0 + qb * k1 + qc * k2 + qd * k3;
    d = reduce8(d);
    float p = __expf(d + (float)(c & 32767u) * weq + bE);
    p = half ? 0.f : p;
    sum += p;
    a0 += p * blo(vv.x);
    a1 += p * bhi(vv.x);
    a2 += p * blo(vv.y);
    a3 += p * bhi(vv.y);
  }

  sum += __shfl_xor(sum, 32, 64);
  a0  += __shfl_xor(a0, 32, 64);
  a1  += __shfl_xor(a1, 32, 64);
  a2  += __shfl_xor(a2, 32, 64);
  a3  += __shfl_xor(a3, 32, 64);

  float inv = 1.f / (sum + 1e-8f);
  if (half == 0) {
    uint2 w;
    w.x = (u32)f2b(a0 * inv) | ((u32)f2b(a1 * inv) << 16);
    w.y = (u32)f2b(a2 * inv) | ((u32)f2b(a3 * inv) << 16);
    *(uint2*)(Qb32 + (size_t)node * 64 + hl * 2) = w;
  }
}

// ---------------------------------------------------------------------------
extern "C" void kernel_launch(void* const* d_in, const int* in_sizes, int n_in,
                              void* d_out, int out_size, void* d_ws, size_t ws_size,
                              hipStream_t stream) {
  const float* nf = (const float*)d_in[0];
  const int*   ei = (const int*)  d_in[1];
  const float* ew = (const float*)d_in[2];
  const float* Wq = (const float*)d_in[3];
  const float* bq = (const float*)d_in[4];
  const float* Wk = (const float*)d_in[5];
  const float* bk = (const float*)d_in[6];
  const float* Wv = (const float*)d_in[7];
  const float* bv = (const float*)d_in[8];
  const float* Wo = (const float*)d_in[9];
  const float* bo = (const float*)d_in[10];
  const float* We = (const float*)d_in[11];
  const float* be = (const float*)d_in[12];
  float* out = (float*)d_out;

  char* ws = (char*)d_ws;
  u16*  Wt  = (u16*)ws;                                 // 128 KB
  u16*  Qb  = (u16*)(ws + 131072);                      // 25.6 MB
  u8*   Kf8 = (u8*)(Qb + (size_t)N_NODES * 128);        // 12.8 MB
  u16*  Vb16 = (u16*)(Kf8 + (size_t)N_NODES * 128);     // 25.6 MB
  char* p   = (char*)(Vb16 + (size_t)N_NODES * 128);
  uint2* stag = (uint2*)p;              p += (size_t)NBUK * BCAP * 8;  // 16.1 MB
  u32*  csr = (u32*)p;                  p += (size_t)NBUK * BCAP * 4;  // 8.0 MB
  int2* nodeinfo = (int2*)p;            p += (size_t)N_NODES * 8;      // 0.8 MB
  u32*  bcur = (u32*)p;                 p += 512;

  setup<<<(NBUK + 65536 + 255) / 256, 256, 0, stream>>>(Wq, Wk, Wv, Wo, Wt, bcur);

  qkv_pass1<<<MBLOCKS + ECHUNKS, 256, 0, stream>>>(
      nf, Wt, bq, bk, bv, Qb, Kf8, Vb16, N_NODES, ei, ew, bcur, stag);

  pass2_scatter<<<NBUK, 1024, 0, stream>>>(bcur, stag, nodeinfo, csr);

  gather_fused<<<N_NODES / 4, 256, 0, stream>>>(nodeinfo, csr,
      (u32*)Qb, Kf8, (const u32*)Vb16, We, be);

  gemm_out<<<MBLOCKS, 256, 0, stream>>>(Qb, Wt + 49152, bo, out, N_NODES);
}

// Round 8
// 276.112 us; speedup vs baseline: 1.4783x; 1.0079x over previous
//
#include <hip/hip_runtime.h>

#define N_NODES 100000
#define E_EDGES 1600000
// D = HID = 128, H = 4, HD = 32

typedef unsigned short u16;
typedef unsigned int   u32;
typedef unsigned char  u8;
typedef float f32x4  __attribute__((ext_vector_type(4)));
typedef short bf16x8 __attribute__((ext_vector_type(8)));

#define NBUK 98            // buckets of 1024 nodes: bucket = tgt >> 10
#define BCAP 20480         // fixed bucket capacity (mean 16384, +32 sigma)
#define MBLOCKS 1563       // ceil(N_NODES/64)
#define ECHUNKS 391        // ceil(E_EDGES/4096)

__device__ __forceinline__ u16 f2b(float f) {
  u32 b = __float_as_uint(f);
  return (u16)((b + 0x7FFFu + ((b >> 16) & 1u)) >> 16);
}
__device__ __forceinline__ float blo(u32 u) { return __uint_as_float(u << 16); }
__device__ __forceinline__ float bhi(u32 u) { return __uint_as_float(u & 0xFFFF0000u); }

// f32 -> OCP e4m3fn, round-to-nearest-even. |f| must be < 448 (holds: |K|<2).
__device__ __forceinline__ u8 f2e4m3(float f) {
  u32 b = __float_as_uint(f);
  u32 s = (b >> 24) & 0x80u;
  float y = __uint_as_float(b & 0x7fffffffu) * 0x1p-120f;
  u32 u = __float_as_uint(y);
  u += 0x7FFFFu + ((u >> 20) & 1u);
  return (u8)(s | ((u >> 20) & 0x7fu));
}

// fallback single-byte e4m3fn -> f32
__device__ __forceinline__ float e4m3_1(u32 x) {
  u32 y = ((x & 0x80u) << 24) | ((x & 0x7fu) << 20);
  return __uint_as_float(y) * 0x1p120f;
}

// decode 4 packed e4m3fn bytes -> 4 floats
__device__ __forceinline__ void dec4(u32 kq, float& k0, float& k1, float& k2, float& k3) {
#if __has_builtin(__builtin_amdgcn_cvt_pk_f32_fp8)
  auto lo = __builtin_amdgcn_cvt_pk_f32_fp8((int)kq, false);   // bytes 0,1
  auto hi = __builtin_amdgcn_cvt_pk_f32_fp8((int)kq, true);    // bytes 2,3
  k0 = lo[0]; k1 = lo[1]; k2 = hi[0]; k3 = hi[1];
#else
  k0 = e4m3_1(kq); k1 = e4m3_1(kq >> 8); k2 = e4m3_1(kq >> 16); k3 = e4m3_1(kq >> 24);
#endif
}

template<int CTRL>
__device__ __forceinline__ float dpp_add(float d) {
  int x = __builtin_amdgcn_update_dpp(0, __float_as_int(d), CTRL, 0xf, 0xf, true);
  return d + __int_as_float(x);
}
// Reduce across an 8-lane group: xor1, xor2 (quad_perm), then half-row mirror.
__device__ __forceinline__ float reduce8(float d) {
  d = dpp_add<0xB1>(d);    // quad_perm [1,0,3,2]
  d = dpp_add<0x4E>(d);    // quad_perm [2,3,0,1]
  d = dpp_add<0x141>(d);   // row_half_mirror
  return d;
}

// ---------------------------------------------------------------------------
// setup: init bucket cursors to fixed window bases AND transpose+convert W.
// ---------------------------------------------------------------------------
__global__ __launch_bounds__(256) void setup(
    const float* __restrict__ Wq, const float* __restrict__ Wk,
    const float* __restrict__ Wv, const float* __restrict__ Wo,
    u16* __restrict__ Wt, u32* __restrict__ bcur)
{
  int tid = blockIdx.x * 256 + threadIdx.x;
  if (tid < NBUK) bcur[tid] = (u32)tid * BCAP;
  int idx = tid - NBUK;
  if (idx >= 0 && idx < 65536) {
    int mat = idx >> 14;
    int rem = idx & 16383;
    int n = rem >> 7, k = rem & 127;
    const float* W = (mat == 0) ? Wq : (mat == 1) ? Wk : (mat == 2) ? Wv : Wo;
    Wt[idx] = f2b(W[k * 128 + n]);
  }
}

// ---------------------------------------------------------------------------
// Fused block-role kernel: blocks [0, MBLOCKS) run the QKV GEMM; blocks
// [MBLOCKS, MBLOCKS+ECHUNKS) run pass1 edge binning.
// Occupancy fix (round 7 theory): A-tile NOT staged in LDS (each A-row is
// consumed by exactly one wave -> zero reuse; lanes hold their row-slice in
// registers). Pass1 writes stag directly from registers (scattered 8B plain
// stores, L2-cached — NOT atomics). LDS arena = Blds only, 34.8 KB
// -> 4 blocks/CU (was 3 at 52 KB).
// ---------------------------------------------------------------------------
__global__ __launch_bounds__(256) void qkv_pass1(
    const float* __restrict__ A, const u16* __restrict__ Wt,
    const float* __restrict__ bq, const float* __restrict__ bk,
    const float* __restrict__ bv,
    u16* __restrict__ Qb, u8* __restrict__ Kf8, u16* __restrict__ Vb16, int M,
    const int* __restrict__ ei, const float* __restrict__ ew,
    u32* __restrict__ bcur, uint2* __restrict__ stag)
{
  __shared__ __align__(16) char smem[34816];
  const int t = threadIdx.x;

  if ((int)blockIdx.x < MBLOCKS) {
    // ---------------- QKV GEMM role ----------------
    typedef u16 row136[136];
    row136* Blds = (row136*)smem;              // 128 x 136 u16 = 34816 B
    const int row0 = blockIdx.x * 64;

    const int lane = t & 63;
    const int mrow = lane & 15;
    const int q    = lane >> 4;
    const int m0   = (t >> 6) * 16;

    // A row-slice -> registers (converted once, reused for all 3 matrices).
    // Lane owns row (row0+m0+mrow), k-chunks kb = kk*32+q*8, kk=0..3.
    int gr = row0 + m0 + mrow; if (gr >= M) gr = M - 1;
    const float4* Arow = (const float4*)(A + (size_t)gr * 128);
    bf16x8 areg[4];
#pragma unroll
    for (int kk = 0; kk < 4; ++kk) {
      float4 v0 = Arow[kk * 8 + q * 2];
      float4 v1 = Arow[kk * 8 + q * 2 + 1];
      union { bf16x8 v; u32 u[4]; } cv;
      cv.u[0] = (u32)f2b(v0.x) | ((u32)f2b(v0.y) << 16);
      cv.u[1] = (u32)f2b(v0.z) | ((u32)f2b(v0.w) << 16);
      cv.u[2] = (u32)f2b(v1.x) | ((u32)f2b(v1.y) << 16);
      cv.u[3] = (u32)f2b(v1.z) | ((u32)f2b(v1.w) << 16);
      areg[kk] = cv.v;
    }

    for (int m = 0; m < 3; ++m) {
      __syncthreads();   // Blds free (prev epilogue done reading it)
#pragma unroll
      for (int i = 0; i < 8; ++i) {
        int f = t + i * 256;
        int r = f >> 4, c8 = f & 15;
        uint4 v = ((const uint4*)(Wt + (size_t)m * 16384 + (size_t)r * 128))[c8];
        *(uint4*)&Blds[r][c8 * 8] = v;
      }
      __syncthreads();

      f32x4 acc[8];
#pragma unroll
      for (int c = 0; c < 8; ++c) acc[c] = (f32x4){0.f, 0.f, 0.f, 0.f};
#pragma unroll
      for (int kk = 0; kk < 4; ++kk) {
        const int kb = kk * 32 + q * 8;
        bf16x8 a = areg[kk];
#pragma unroll
        for (int c = 0; c < 8; ++c) {
          bf16x8 b = *(const bf16x8*)&Blds[c * 16 + mrow][kb];
          acc[c] = __builtin_amdgcn_mfma_f32_16x16x32_bf16(a, b, acc[c], 0, 0, 0);
        }
      }

      const float* bias = (m == 0) ? bq : (m == 1) ? bk : bv;
      __syncthreads();   // all waves done reading Blds -> reuse as staging
      if (m == 1) {
        // K: stage e4m3 bytes (row stride 144 B, 16B-aligned, conflict-padded)
        u8* Kst = (u8*)smem;
#pragma unroll
        for (int c = 0; c < 8; ++c) {
          int gcol = c * 16 + mrow;
          float bvv = bias[gcol];
#pragma unroll
          for (int r = 0; r < 4; ++r)
            Kst[(m0 + q * 4 + r) * 144 + gcol] = f2e4m3(acc[c][r] + bvv);
        }
        __syncthreads();
#pragma unroll
        for (int i = 0; i < 2; ++i) {
          int f = t + i * 256;
          int r = f >> 3, c16 = f & 7;
          int grow = row0 + r;
          if (grow < M)
            *(uint4*)(Kf8 + (size_t)grow * 128 + c16 * 16) =
                *(const uint4*)(Kst + r * 144 + c16 * 16);
        }
      } else {
        // Q / V: stage bf16 (row stride 136 u16 = 272 B, 16B-aligned, padded)
        u16* St = (u16*)smem;
#pragma unroll
        for (int c = 0; c < 8; ++c) {
          int gcol = c * 16 + mrow;
          float bvv = bias[gcol];
#pragma unroll
          for (int r = 0; r < 4; ++r)
            St[(m0 + q * 4 + r) * 136 + gcol] = f2b(acc[c][r] + bvv);
        }
        __syncthreads();
        u16* dstM = (m == 0) ? Qb : Vb16;
#pragma unroll
        for (int i = 0; i < 4; ++i) {
          int f = t + i * 256;
          int r = f >> 4, c8 = f & 15;
          int grow = row0 + r;
          if (grow < M)
            *(uint4*)(dstM + (size_t)grow * 128 + c8 * 8) =
                *(const uint4*)(St + r * 136 + c8 * 8);
        }
      }
    }
  } else {
    // ---------------- pass1 edge-binning role ----------------
    u32* s_hist  = (u32*)smem;               // NBUK
    u32* s_excl  = (u32*)(smem + 512);       // NBUK
    u32* s_gbase = (u32*)(smem + 1024);      // NBUK
    u32* s_wsum  = (u32*)(smem + 1536);      // 4

    const int base = ((int)blockIdx.x - MBLOCKS) * 4096;
    const int nv = min(4096, E_EDGES - base);   // nv % 4 == 0 always

    if (t < NBUK) s_hist[t] = 0;
    __syncthreads();

    u32 tg[16], py[16];
    const int4*   src4 = (const int4*)(ei + base);
    const int4*   tgt4 = (const int4*)(ei + E_EDGES + base);
    const float4* ewv4 = (const float4*)(ew + base);
#pragma unroll
    for (int j = 0; j < 4; ++j) {
      int q4 = t + j * 256;                 // int4 index
      bool valid = (q4 * 4) < nv;           // whole-vector validity (nv%4==0)
      int qq = valid ? q4 : 0;
      int4   sv = src4[qq];
      int4   tv = tgt4[qq];
      float4 wv = ewv4[qq];
      u32* TG = &tg[j * 4];
      u32* PY = &py[j * 4];
      TG[0] = (u32)tv.x; TG[1] = (u32)tv.y; TG[2] = (u32)tv.z; TG[3] = (u32)tv.w;
      PY[0] = ((u32)sv.x << 15) | (u32)(wv.x * 32768.0f);
      PY[1] = ((u32)sv.y << 15) | (u32)(wv.y * 32768.0f);
      PY[2] = ((u32)sv.z << 15) | (u32)(wv.z * 32768.0f);
      PY[3] = ((u32)sv.w << 15) | (u32)(wv.w * 32768.0f);
      if (valid) {
        atomicAdd(&s_hist[TG[0] >> 10], 1u);
        atomicAdd(&s_hist[TG[1] >> 10], 1u);
        atomicAdd(&s_hist[TG[2] >> 10], 1u);
        atomicAdd(&s_hist[TG[3] >> 10], 1u);
      } else {
        TG[0] = TG[1] = TG[2] = TG[3] = 0xFFFFFFFFu;
      }
    }
    __syncthreads();

    // scan 98 bucket counts: 64-lane shfl scans + cross-wave fixup
    {
      int v = (t < NBUK) ? (int)s_hist[t] : 0;
      int x = v;
#pragma unroll
      for (int d = 1; d < 64; d <<= 1) {
        int y = __shfl_up(x, d, 64);
        if ((t & 63) >= d) x += y;
      }
      if ((t & 63) == 63 && t < 128) s_wsum[t >> 6] = (u32)x;
      __syncthreads();
      if (t < NBUK) {
        int incl = x + ((t >= 64) ? (int)s_wsum[0] : 0);
        s_excl[t] = (u32)(incl - v);
        s_gbase[t] = (v > 0) ? atomicAdd(&bcur[t], (u32)v) : 0u;
      }
    }
    __syncthreads();
    if (t < NBUK) s_hist[t] = s_excl[t];   // reuse as LDS cursor
    __syncthreads();

    // claim slot via LDS cursor, write stag directly from registers
    // (plain scattered 8B stores, bucket-contiguous-ish; in-bucket order
    //  is arbitrary — pass2 re-sorts per node)
#pragma unroll
    for (int i = 0; i < 16; ++i) {
      if (tg[i] != 0xFFFFFFFFu) {
        u32 bk = tg[i] >> 10;
        u32 lp = atomicAdd(&s_hist[bk], 1u);
        u32 dest = s_gbase[bk] + (lp - s_excl[bk]);
        stag[dest] = make_uint2(tg[i], py[i]);
      }
    }
  }
}

// ---------------------------------------------------------------------------
// Final: out(Mx128,f32) = A(bf16, Mx128) @ Wo + bo
// A loaded per-wave directly from global (bf16, no conversion, no reuse
// across waves -> no LDS); W staged in Blds; epilogue staged through the
// same arena -> coalesced NONTEMPORAL float4 stores.  LDS 34.8 KB.
// ---------------------------------------------------------------------------
__global__ __launch_bounds__(256) void gemm_out(
    const u16* __restrict__ Aq, const u16* __restrict__ Wt,
    const float* __restrict__ bias, float* __restrict__ Cout, int M)
{
  __shared__ __align__(16) char smem[34816];
  typedef u16 row136[136];
  row136* Blds = (row136*)smem;
  const int t = threadIdx.x;
  const int row0 = blockIdx.x * 64;

#pragma unroll
  for (int i = 0; i < 8; ++i) {
    int f = t + i * 256;
    int r = f >> 4, c8 = f & 15;
    uint4 v = ((const uint4*)(Wt + (size_t)r * 128))[c8];
    *(uint4*)&Blds[r][c8 * 8] = v;
  }

  const int lane = t & 63;
  const int mrow = lane & 15;
  const int q    = lane >> 4;
  const int m0   = (t >> 6) * 16;

  // lane's A row-slice, direct from global (bf16)
  int gr = row0 + m0 + mrow; if (gr >= M) gr = M - 1;
  const bf16x8* Arow = (const bf16x8*)(Aq + (size_t)gr * 128);
  bf16x8 areg[4];
#pragma unroll
  for (int kk = 0; kk < 4; ++kk) areg[kk] = Arow[kk * 4 + q];

  __syncthreads();

  f32x4 acc[8];
#pragma unroll
  for (int c = 0; c < 8; ++c) acc[c] = (f32x4){0.f, 0.f, 0.f, 0.f};
#pragma unroll
  for (int kk = 0; kk < 4; ++kk) {
    const int kb = kk * 32 + q * 8;
    bf16x8 a = areg[kk];
#pragma unroll
    for (int c = 0; c < 8; ++c) {
      bf16x8 b = *(const bf16x8*)&Blds[c * 16 + mrow][kb];
      acc[c] = __builtin_amdgcn_mfma_f32_16x16x32_bf16(a, b, acc[c], 0, 0, 0);
    }
  }

  // stage f32 tile (64 x 128, padded stride 132 f32 = 33792 B) into the arena
  __syncthreads();   // all waves done reading Blds
  float* Fst = (float*)smem;
#pragma unroll
  for (int c = 0; c < 8; ++c) {
    int gcol = c * 16 + mrow;
    float bv = bias[gcol];
#pragma unroll
    for (int r = 0; r < 4; ++r)
      Fst[(m0 + q * 4 + r) * 132 + gcol] = acc[c][r] + bv;
  }
  __syncthreads();
#pragma unroll
  for (int i = 0; i < 8; ++i) {
    int f = t + i * 256;
    int r = f >> 5, c4 = f & 31;
    int grow = row0 + r;
    if (grow < M) {
      f32x4 vv = *(const f32x4*)(Fst + r * 132 + c4 * 4);
      __builtin_nontemporal_store(vv, (f32x4*)(Cout + (size_t)grow * 128 + c4 * 4));
    }
  }
}

// ---------------------------------------------------------------------------
// pass2: one block per bucket. Single global read of stag into REGISTERS
// (20-deep unrolled, static-indexed, nontemporal); LDS per-node histogram +
// shfl scan -> nodeinfo {start,deg}; scatter from registers via LDS cursors
// into the bucket's csr window.  [round-5 structure — measured good]
// ---------------------------------------------------------------------------
__global__ __launch_bounds__(1024) void pass2_scatter(
    const u32* __restrict__ bcur, const uint2* __restrict__ stag,
    int2* __restrict__ nodeinfo, u32* __restrict__ csr)
{
  __shared__ int s_hist[1024];
  __shared__ int s_wsum[16];
  const int t = threadIdx.x;
  const int b = blockIdx.x;
  const int sb = b * BCAP;
  const int cnt = (int)bcur[b] - sb;
  const int node_base = b << 10;

  s_hist[t] = 0;
  __syncthreads();

  // single pass over stag: payload + node-id into registers, histogram to LDS
  typedef unsigned long long u64;
  const u64* sg = (const u64*)stag;
  u32 tgr[20], pyr[20];
#pragma unroll
  for (int k = 0; k < 20; ++k) {
    int i = t + k * 1024;
    if (i < cnt) {
      u64 e = __builtin_nontemporal_load(sg + sb + i);
      tgr[k] = (u32)e & 1023u;
      pyr[k] = (u32)(e >> 32);
      atomicAdd(&s_hist[tgr[k]], 1);
    } else {
      tgr[k] = 0xFFFFFFFFu;
      pyr[k] = 0u;
    }
  }
  __syncthreads();

  // hierarchical inclusive scan of 1024 counts
  int v = s_hist[t];
  int x = v;
#pragma unroll
  for (int d = 1; d < 64; d <<= 1) {
    int y = __shfl_up(x, d, 64);
    if ((t & 63) >= d) x += y;
  }
  if ((t & 63) == 63) s_wsum[t >> 6] = x;
  __syncthreads();
  if (t < 64) {
    int w = (t < 16) ? s_wsum[t] : 0;
#pragma unroll
    for (int d = 1; d < 16; d <<= 1) {
      int y = __shfl_up(w, d, 64);
      if (t >= d) w += y;
    }
    if (t < 16) s_wsum[t] = w;   // inclusive wave-sum prefix
  }
  __syncthreads();
  int wbase = (t >= 64) ? s_wsum[(t >> 6) - 1] : 0;
  int excl = x + wbase - v;
  int node = node_base + t;
  if (node < N_NODES) nodeinfo[node] = make_int2(sb + excl, v);
  __syncthreads();
  s_hist[t] = sb + excl;   // absolute cursor
  __syncthreads();

  // scatter from registers
#pragma unroll
  for (int k = 0; k < 20; ++k) {
    if (tgr[k] != 0xFFFFFFFFu) {
      int pos = atomicAdd(&s_hist[tgr[k]], 1);
      csr[pos] = pyr[k];
    }
  }
}

// ---------------------------------------------------------------------------
// Fused per-node gather, 2 edges per wave (lanes 0-31 even edges, 32-63 odd),
// 4-pair unroll -> 8 edges in flight per wave.  [FROZEN since round 3]
// Within a half: 8 lanes/head, lane owns elems [4hl..4hl+3]:
//   K: one dword of fp8 at Krow + 4*hl   (row = 128 B = 1 cache line)
//   V: one dwordx2 of bf16 at Vrow + 8*hl (row = 256 B = 2 lines)
// ---------------------------------------------------------------------------
__global__ __launch_bounds__(256) void gather_fused(
    const int2* __restrict__ nodeinfo, const u32* __restrict__ csr,
    u32* __restrict__ Qb32, const u8* __restrict__ Kf8,
    const u32* __restrict__ Vb,
    const float* __restrict__ We, const float* __restrict__ be)
{
  int node = blockIdx.x * 4 + (threadIdx.x >> 6);
  int l    = threadIdx.x & 63;
  int half = l >> 5;
  int hl   = l & 31;
  int h    = hl >> 3;

  const float scale = 0.17677669529663687f;   // 1/sqrt(32)
  const float eiq   = 1.0f / 32768.0f;
  uint2 qp = *(const uint2*)(Qb32 + (size_t)node * 64 + hl * 2);
  float qa = blo(qp.x) * scale, qb = bhi(qp.x) * scale;
  float qc = blo(qp.y) * scale, qd = bhi(qp.y) * scale;
  float weq = We[h] * eiq, bE = be[h];
  const u32 laneK = (u32)hl * 4;
  const u32 laneV = (u32)hl * 8;

  int2 ni = nodeinfo[node];
  int s0 = ni.x, L = ni.y;
  int npair = L >> 1;
  const u32* cp = csr + s0 + half;
  const char* Kc = (const char*)Kf8;
  const char* Vc = (const char*)Vb;

  float a0 = 0.f, a1 = 0.f, a2 = 0.f, a3 = 0.f, sum = 0.f;

  auto LDK = [&](u32 c) -> u32 {
    return *(const u32*)(Kc + (((c >> 15) << 7) + laneK));
  };
  auto LDV = [&](u32 c) -> uint2 {
    return *(const uint2*)(Vc + (((c >> 15) << 8) + laneV));
  };
  auto COMP = [&](u32 c, u32 kq, uint2 vv) {
    float k0, k1, k2, k3;
    dec4(kq, k0, k1, k2, k3);
    float d = qa * k0 + qb * k1 + qc * k2 + qd * k3;
    d = reduce8(d);
    float p = __expf(d + (float)(c & 32767u) * weq + bE);
    sum += p;
    a0 += p * blo(vv.x);
    a1 += p * bhi(vv.x);
    a2 += p * blo(vv.y);
    a3 += p * bhi(vv.y);
  };

  int i = 0;
  for (; i + 4 <= npair; i += 4) {
    u32 c0 = cp[2 * i];
    u32 c1 = cp[2 * i + 2];
    u32 c2 = cp[2 * i + 4];
    u32 c3 = cp[2 * i + 6];
    u32 k0 = LDK(c0), k1 = LDK(c1), k2 = LDK(c2), k3 = LDK(c3);
    uint2 v0 = LDV(c0), v1 = LDV(c1), v2 = LDV(c2), v3 = LDV(c3);
    COMP(c0, k0, v0);
    COMP(c1, k1, v1);
    COMP(c2, k2, v2);
    COMP(c3, k3, v3);
  }
  for (; i < npair; ++i) {
    u32 c = cp[2 * i];
    u32 kq = LDK(c);
    uint2 vv = LDV(c);
    COMP(c, kq, vv);
  }
  // odd final edge: both halves load it, half 1 contributes 0
  if (L & 1) {
    u32 c = csr[s0 + L - 1];
    u32 kq = LDK(c);
    uint2 vv = LDV(c);
    float k0, k1, k2, k3;
    dec4(kq, k0, k1, k2, k3);
    float d = qa * k0 + qb * k1 + qc * k2 + qd * k3;
    d = reduce8(d);
    float p = __expf(d + (float)(c & 32767u) * weq + bE);
    p = half ? 0.f : p;
    sum += p;
    a0 += p * blo(vv.x);
    a1 += p * bhi(vv.x);
    a2 += p * blo(vv.y);
    a3 += p * bhi(vv.y);
  }

  sum += __shfl_xor(sum, 32, 64);
  a0  += __shfl_xor(a0, 32, 64);
  a1  += __shfl_xor(a1, 32, 64);
  a2  += __shfl_xor(a2, 32, 64);
  a3  += __shfl_xor(a3, 32, 64);

  float inv = 1.f / (sum + 1e-8f);
  if (half == 0) {
    uint2 w;
    w.x = (u32)f2b(a0 * inv) | ((u32)f2b(a1 * inv) << 16);
    w.y = (u32)f2b(a2 * inv) | ((u32)f2b(a3 * inv) << 16);
    *(uint2*)(Qb32 + (size_t)node * 64 + hl * 2) = w;
  }
}

// ---------------------------------------------------------------------------
extern "C" void kernel_launch(void* const* d_in, const int* in_sizes, int n_in,
                              void* d_out, int out_size, void* d_ws, size_t ws_size,
                              hipStream_t stream) {
  const float* nf = (const float*)d_in[0];
  const int*   ei = (const int*)  d_in[1];
  const float* ew = (const float*)d_in[2];
  const float* Wq = (const float*)d_in[3];
  const float* bq = (const float*)d_in[4];
  const float* Wk = (const float*)d_in[5];
  const float* bk = (const float*)d_in[6];
  const float* Wv = (const float*)d_in[7];
  const float* bv = (const float*)d_in[8];
  const float* Wo = (const float*)d_in[9];
  const float* bo = (const float*)d_in[10];
  const float* We = (const float*)d_in[11];
  const float* be = (const float*)d_in[12];
  float* out = (float*)d_out;

  char* ws = (char*)d_ws;
  u16*  Wt  = (u16*)ws;                                 // 128 KB
  u16*  Qb  = (u16*)(ws + 131072);                      // 25.6 MB
  u8*   Kf8 = (u8*)(Qb + (size_t)N_NODES * 128);        // 12.8 MB
  u16*  Vb16 = (u16*)(Kf8 + (size_t)N_NODES * 128);     // 25.6 MB
  char* p   = (char*)(Vb16 + (size_t)N_NODES * 128);
  uint2* stag = (uint2*)p;              p += (size_t)NBUK * BCAP * 8;  // 16.1 MB
  u32*  csr = (u32*)p;                  p += (size_t)NBUK * BCAP * 4;  // 8.0 MB
  int2* nodeinfo = (int2*)p;            p += (size_t)N_NODES * 8;      // 0.8 MB
  u32*  bcur = (u32*)p;                 p += 512;

  setup<<<(NBUK + 65536 + 255) / 256, 256, 0, stream>>>(Wq, Wk, Wv, Wo, Wt, bcur);

  qkv_pass1<<<MBLOCKS + ECHUNKS, 256, 0, stream>>>(
      nf, Wt, bq, bk, bv, Qb, Kf8, Vb16, N_NODES, ei, ew, bcur, stag);

  pass2_scatter<<<NBUK, 1024, 0, stream>>>(bcur, stag, nodeinfo, csr);

  gather_fused<<<N_NODES / 4, 256, 0, stream>>>(nodeinfo, csr,
      (u32*)Qb, Kf8, (const u32*)Vb16, We, be);

  gemm_out<<<MBLOCKS, 256, 0, stream>>>(Qb, Wt + 49152, bo, out, N_NODES);
}